// Round 16
// baseline (257.983 us; speedup 1.0000x reference)
//
#include <hip/hip_runtime.h>
#include <hip/hip_bf16.h>

static constexpr int NN = 50000;
static constexpr int NE = 800000;
static constexpr float BN_EPS = 1e-5f;

static constexpr int NB  = 128;    // dst buckets
static constexpr int NPB = 391;    // nodes per bucket
static constexpr int CAP = 8192;   // tmp slots per bucket
static constexpr int CHUNK = 2048;
static constexpr int NR   = 8;     // src ranges (gather L2 locality)
static constexpr int SRNG = 6250;  // src-range width -> 0.8MB p-slice

static constexpr int BINABLK  = (NE + CHUNK - 1) / CHUNK;  // 391
static constexpr int PROJ0BLK = (NN + 63) / 64;            // 782

typedef short bf16x8 __attribute__((ext_vector_type(8)));
typedef float f32x4 __attribute__((ext_vector_type(4)));

__device__ __forceinline__ float bflo(unsigned u) { return __uint_as_float(u << 16); }
__device__ __forceinline__ float bfhi(unsigned u) { return __uint_as_float(u & 0xffff0000u); }
__device__ __forceinline__ unsigned short f2bf(float f) {
    unsigned u = __float_as_uint(f);
    unsigned r = (u + 0x7fffu + ((u >> 16) & 1u)) >> 16;
    return (unsigned short)r;
}

// ===========================================================================
// zero: stats (512 f) + gcount (NB ints), contiguous
// ===========================================================================
__global__ __launch_bounds__(256) void zero_kernel(int* __restrict__ ptr, int n)
{
    int i = blockIdx.x * 256 + threadIdx.x;
    if (i < n) ptr[i] = 0;
}

// ===========================================================================
// fat_kernel: blocks [0,BINABLK) = binA; [BINABLK,+PROJ0BLK) = proj0 MFMA.
// ===========================================================================
struct SmBinA {
    unsigned stage[CHUNK];
    int hist[NB], base[NB], gpos[NB];
};
struct SmProj0 {
    unsigned short Wt[64][136];
};

__device__ __forceinline__ void binA_body(
    SmBinA& sm, const int* __restrict__ src, const int* __restrict__ dst,
    int* __restrict__ gcount, unsigned* __restrict__ tmp, int blk)
{
    const int t = threadIdx.x;
    const int cb = blk * CHUNK;
    const int total = min(CHUNK, NE - cb);

    if (t < NB) sm.hist[t] = 0;
    __syncthreads();

    int mb[8], mslot[8];
    unsigned mv[8];
    #pragma unroll
    for (int k = 0; k < 8; ++k) {
        int e = cb + k * 256 + t;
        mb[k] = -1;
        if (e < NE) {
            int s = src[e];
            int d = dst[e];
            int b = d / NPB;
            mb[k] = b;
            mv[k] = ((unsigned)d << 16) | (unsigned)s;
            mslot[k] = atomicAdd(&sm.hist[b], 1);
        }
    }
    __syncthreads();

    if (t < NB) sm.base[t] = sm.hist[t];
    __syncthreads();
    for (int ofs = 1; ofs < NB; ofs <<= 1) {
        int v = (t >= ofs && t < NB) ? sm.base[t - ofs] : 0;
        __syncthreads();
        if (t < NB) sm.base[t] += v;
        __syncthreads();
    }
    if (t < NB && sm.hist[t] > 0)
        sm.gpos[t] = t * CAP + atomicAdd(&gcount[t], sm.hist[t]);
    __syncthreads();

    #pragma unroll
    for (int k = 0; k < 8; ++k) {
        if (mb[k] >= 0) {
            int b = mb[k];
            sm.stage[(sm.base[b] - sm.hist[b]) + mslot[k]] = mv[k];
        }
    }
    __syncthreads();

    for (int i = t; i < total; i += 256) {
        unsigned v = sm.stage[i];
        int b = (int)(v >> 16) / NPB;
        int pos = sm.gpos[b] + (i - (sm.base[b] - sm.hist[b]));
        tmp[pos] = v;
    }
}

__device__ __forceinline__ void proj0_body(
    SmProj0& sm, const float* __restrict__ hin, const float* __restrict__ W1,
    unsigned short* __restrict__ p, int blk)
{
    const int t = threadIdx.x;
    for (int i = t; i < 128 * 16; i += 256) {
        int k = i >> 4, c0 = (i & 15) * 4;
        float4 w = *reinterpret_cast<const float4*>(W1 + (size_t)k * 64 + c0);
        sm.Wt[c0 + 0][k] = f2bf(w.x); sm.Wt[c0 + 1][k] = f2bf(w.y);
        sm.Wt[c0 + 2][k] = f2bf(w.z); sm.Wt[c0 + 3][k] = f2bf(w.w);
    }
    __syncthreads();

    const int wv = t >> 6;
    const int l = t & 63;
    const int g = l >> 4;
    const int cl = l & 15;
    const int rowbase = blk * 64 + wv * 16;

    int ar = min(rowbase + cl, NN - 1);
    const float* hrow = hin + (size_t)ar * 128;
    bf16x8 a[4];
    #pragma unroll
    for (int kk = 0; kk < 4; ++kk) {
        float4 f0 = *reinterpret_cast<const float4*>(hrow + kk * 32 + 8 * g);
        float4 f1 = *reinterpret_cast<const float4*>(hrow + kk * 32 + 8 * g + 4);
        unsigned short oo[8] = { f2bf(f0.x), f2bf(f0.y), f2bf(f0.z), f2bf(f0.w),
                                 f2bf(f1.x), f2bf(f1.y), f2bf(f1.z), f2bf(f1.w) };
        a[kk] = *reinterpret_cast<bf16x8*>(oo);
    }

    f32x4 acc[4];
    #pragma unroll
    for (int ct = 0; ct < 4; ++ct) acc[ct] = (f32x4){0.f, 0.f, 0.f, 0.f};

    #pragma unroll
    for (int ct = 0; ct < 4; ++ct) {
        #pragma unroll
        for (int kk = 0; kk < 4; ++kk) {
            bf16x8 w = *reinterpret_cast<const bf16x8*>(
                &sm.Wt[ct * 16 + cl][kk * 32 + 8 * g]);
            acc[ct] = __builtin_amdgcn_mfma_f32_16x16x32_bf16(w, a[kk], acc[ct], 0, 0, 0);
        }
    }

    int gr = rowbase + cl;
    if (gr < NN) {
        #pragma unroll
        for (int ct = 0; ct < 4; ++ct) {
            unsigned lo = (unsigned)f2bf(acc[ct][0]) | ((unsigned)f2bf(acc[ct][1]) << 16);
            unsigned hi = (unsigned)f2bf(acc[ct][2]) | ((unsigned)f2bf(acc[ct][3]) << 16);
            *reinterpret_cast<uint2*>(p + (size_t)gr * 64 + ct * 16 + 4 * g) =
                make_uint2(lo, hi);
        }
    }
}

__global__ __launch_bounds__(256) void fat_kernel(
    const int* __restrict__ src, const int* __restrict__ dst,
    int* __restrict__ gcount, unsigned* __restrict__ tmp,
    const float* __restrict__ hin, const float* __restrict__ W1,
    unsigned short* __restrict__ p)
{
    __shared__ union { SmBinA a; SmProj0 w; } sm;
    if (blockIdx.x < BINABLK)
        binA_body(sm.a, src, dst, gcount, tmp, blockIdx.x);
    else
        proj0_body(sm.w, hin, W1, p, blockIdx.x - BINABLK);
}

// ===========================================================================
// binB: per bucket: per-(node,src-range NR=8) hist + scan -> off + eidx
// ===========================================================================
__global__ __launch_bounds__(256) void binB_kernel(
    const unsigned* __restrict__ tmp, const int* __restrict__ gcount,
    int* __restrict__ off, int* __restrict__ eidx)
{
    __shared__ int gb[NB];
    __shared__ int histr[NPB * NR];
    __shared__ int hs[512];
    __shared__ int curr[NPB * NR];
    __shared__ int base_s;

    const int t = threadIdx.x;
    const int b = blockIdx.x;
    const int n0 = b * NPB;
    const int n1 = min(n0 + NPB, NN);
    const int nnodes = n1 - n0;
    const int cnt = gcount[b];

    if (t < NB) gb[t] = gcount[t];
    for (int i = t; i < NPB * NR; i += 256) histr[i] = 0;
    __syncthreads();
    for (int ofs = 1; ofs < NB; ofs <<= 1) {
        int v = (t >= ofs && t < NB) ? gb[t - ofs] : 0;
        __syncthreads();
        if (t < NB) gb[t] += v;
        __syncthreads();
    }
    if (t == 0) base_s = (b == 0) ? 0 : gb[b - 1];
    __syncthreads();
    const int base = base_s;

    const unsigned* tb = tmp + (size_t)b * CAP;
    for (int i = t; i < cnt; i += 256) {
        unsigned v = tb[i];
        int d = (int)(v >> 16);
        int s = (int)(v & 0xffffu);
        atomicAdd(&histr[(d - n0) * NR + s / SRNG], 1);
    }
    __syncthreads();
    {
        int n = t;
        int tot0 = 0, tot1 = 0;
        if (n < NPB) {
            #pragma unroll
            for (int r = 0; r < NR; ++r) tot0 += histr[n * NR + r];
        }
        int n2 = t + 256;
        if (n2 < NPB) {
            #pragma unroll
            for (int r = 0; r < NR; ++r) tot1 += histr[n2 * NR + r];
        }
        hs[t] = tot0;
        hs[t + 256] = tot1;
    }
    __syncthreads();
    for (int ofs = 1; ofs < 512; ofs <<= 1) {
        int a0 = (t >= ofs) ? hs[t - ofs] : 0;
        int a1 = hs[t + 256 - ofs];
        __syncthreads();
        hs[t] += a0;
        hs[t + 256] += a1;
        __syncthreads();
    }
    for (int n = t; n < nnodes; n += 256) {
        int tot = 0;
        #pragma unroll
        for (int r = 0; r < NR; ++r) tot += histr[n * NR + r];
        int c = base + hs[n] - tot;
        off[n0 + n] = c;
        #pragma unroll
        for (int r = 0; r < NR; ++r) {
            curr[n * NR + r] = c;
            c += histr[n * NR + r];
        }
    }
    if (b == NB - 1 && t == 0) off[NN] = base + cnt;
    __syncthreads();
    for (int i = t; i < cnt; i += 256) {
        unsigned v = tb[i];
        int d = (int)(v >> 16);
        int s = (int)(v & 0xffffu);
        int pos = atomicAdd(&curr[(d - n0) * NR + s / SRNG], 1);
        eidx[pos] = s;
    }
}

// ===========================================================================
// proj (layers 1-3): p(bf16) = relu(zb*scale+shift) @ W1, fp32 4x4 tile.
// 64 rows/block (782 blocks -> ~3/CU, small tail).
// ===========================================================================
__global__ __launch_bounds__(256) void proj_kernel(
    const unsigned short* __restrict__ zbin, const float* __restrict__ W1,
    const float* __restrict__ gsum, const float* __restrict__ gsq,
    const float* __restrict__ gamma, const float* __restrict__ beta,
    unsigned short* __restrict__ p)
{
    constexpr int RPB = 64;
    __shared__ float XsT[64][68];
    __shared__ float Ws[64][64];
    __shared__ float scs[64], shs[64];

    const int t = threadIdx.x;
    const int rowbase = blockIdx.x * RPB;

    if (t < 64) {
        const float invn = 1.f / (float)NN;
        float mean = gsum[t] * invn;
        float var  = gsq[t] * invn - mean * mean;
        float sc   = gamma[t] * rsqrtf(var + BN_EPS);
        scs[t] = sc;
        shs[t] = beta[t] - mean * sc;
    }
    __syncthreads();

    {
        const float4* wg = reinterpret_cast<const float4*>(W1);
        float4* wl = reinterpret_cast<float4*>(&Ws[0][0]);
        for (int i = t; i < 64 * 16; i += 256) wl[i] = wg[i];
    }
    {
        const uint4* hb = reinterpret_cast<const uint4*>(zbin);
        int rr = t & 31, q = t >> 5;
        for (int i = 0; i < RPB; i += 32) {
            int r = i + rr;
            int gr = rowbase + r;
            uint4 v = make_uint4(0u, 0u, 0u, 0u);
            if (gr < NN) v = hb[gr * 8 + q];
            int c = q * 8;
            float f0 = bflo(v.x), f1 = bfhi(v.x), f2 = bflo(v.y), f3 = bfhi(v.y);
            float f4 = bflo(v.z), f5 = bfhi(v.z), f6 = bflo(v.w), f7 = bfhi(v.w);
            XsT[c + 0][r] = fmaxf(f0 * scs[c + 0] + shs[c + 0], 0.f);
            XsT[c + 1][r] = fmaxf(f1 * scs[c + 1] + shs[c + 1], 0.f);
            XsT[c + 2][r] = fmaxf(f2 * scs[c + 2] + shs[c + 2], 0.f);
            XsT[c + 3][r] = fmaxf(f3 * scs[c + 3] + shs[c + 3], 0.f);
            XsT[c + 4][r] = fmaxf(f4 * scs[c + 4] + shs[c + 4], 0.f);
            XsT[c + 5][r] = fmaxf(f5 * scs[c + 5] + shs[c + 5], 0.f);
            XsT[c + 6][r] = fmaxf(f6 * scs[c + 6] + shs[c + 6], 0.f);
            XsT[c + 7][r] = fmaxf(f7 * scs[c + 7] + shs[c + 7], 0.f);
        }
    }
    __syncthreads();

    const int tc = t & 15;
    const int tr = t >> 4;
    const int c0 = tc * 4;
    const int r0 = tr * 4;

    float acc[4][4];
    #pragma unroll
    for (int i = 0; i < 4; ++i)
        #pragma unroll
        for (int j = 0; j < 4; ++j) acc[i][j] = 0.f;

    for (int k = 0; k < 64; ++k) {
        float4 xa = *reinterpret_cast<const float4*>(&XsT[k][r0]);
        float4 wa = *reinterpret_cast<const float4*>(&Ws[k][c0]);
        float x[4] = { xa.x, xa.y, xa.z, xa.w };
        float w[4] = { wa.x, wa.y, wa.z, wa.w };
        #pragma unroll
        for (int i = 0; i < 4; ++i)
            #pragma unroll
            for (int j = 0; j < 4; ++j) acc[i][j] += x[i] * w[j];
    }

    #pragma unroll
    for (int i = 0; i < 4; ++i) {
        int gr = rowbase + r0 + i;
        if (gr < NN) {
            unsigned lo = (unsigned)f2bf(acc[i][0]) | ((unsigned)f2bf(acc[i][1]) << 16);
            unsigned hi = (unsigned)f2bf(acc[i][2]) | ((unsigned)f2bf(acc[i][3]) << 16);
            *reinterpret_cast<uint2*>(p + (size_t)gr * 64 + c0) = make_uint2(lo, hi);
        }
    }
}

// ===========================================================================
// gather: Y[i] = relu(p[i] + sum_{j in N(i)} p[j] + b1)   (bf16 in/out)
// ===========================================================================
__global__ __launch_bounds__(256) void gather_kernel(
    const unsigned short* __restrict__ p, const int* __restrict__ off,
    const int* __restrict__ eidx, const float* __restrict__ b1,
    unsigned short* __restrict__ Y)
{
    int gid = blockIdx.x * 256 + threadIdx.x;
    if (gid >= NN * 8) return;
    int row = gid >> 3;
    int q = gid & 7;

    const uint4* pb = reinterpret_cast<const uint4*>(p);
    uint4 u = pb[row * 8 + q];
    float a0 = bflo(u.x), a1 = bfhi(u.x), a2 = bflo(u.y), a3 = bfhi(u.y);
    float a4 = bflo(u.z), a5 = bfhi(u.z), a6 = bflo(u.w), a7 = bfhi(u.w);

    int e = off[row];
    const int end = off[row + 1];
    for (; e + 4 <= end; e += 4) {
        int s0 = eidx[e + 0], s1 = eidx[e + 1];
        int s2 = eidx[e + 2], s3 = eidx[e + 3];
        uint4 v0 = pb[s0 * 8 + q];
        uint4 v1 = pb[s1 * 8 + q];
        uint4 v2 = pb[s2 * 8 + q];
        uint4 v3 = pb[s3 * 8 + q];
        a0 += (bflo(v0.x) + bflo(v1.x)) + (bflo(v2.x) + bflo(v3.x));
        a1 += (bfhi(v0.x) + bfhi(v1.x)) + (bfhi(v2.x) + bfhi(v3.x));
        a2 += (bflo(v0.y) + bflo(v1.y)) + (bflo(v2.y) + bflo(v3.y));
        a3 += (bfhi(v0.y) + bfhi(v1.y)) + (bfhi(v2.y) + bfhi(v3.y));
        a4 += (bflo(v0.z) + bflo(v1.z)) + (bflo(v2.z) + bflo(v3.z));
        a5 += (bfhi(v0.z) + bfhi(v1.z)) + (bfhi(v2.z) + bfhi(v3.z));
        a6 += (bflo(v0.w) + bflo(v1.w)) + (bflo(v2.w) + bflo(v3.w));
        a7 += (bfhi(v0.w) + bfhi(v1.w)) + (bfhi(v2.w) + bfhi(v3.w));
    }
    for (; e < end; ++e) {
        uint4 v = pb[eidx[e] * 8 + q];
        a0 += bflo(v.x); a1 += bfhi(v.x); a2 += bflo(v.y); a3 += bfhi(v.y);
        a4 += bflo(v.z); a5 += bfhi(v.z); a6 += bflo(v.w); a7 += bfhi(v.w);
    }

    float4 blo = reinterpret_cast<const float4*>(b1)[q * 2];
    float4 bhi = reinterpret_cast<const float4*>(b1)[q * 2 + 1];
    a0 = fmaxf(a0 + blo.x, 0.f); a1 = fmaxf(a1 + blo.y, 0.f);
    a2 = fmaxf(a2 + blo.z, 0.f); a3 = fmaxf(a3 + blo.w, 0.f);
    a4 = fmaxf(a4 + bhi.x, 0.f); a5 = fmaxf(a5 + bhi.y, 0.f);
    a6 = fmaxf(a6 + bhi.z, 0.f); a7 = fmaxf(a7 + bhi.w, 0.f);

    uint4 o;
    o.x = (unsigned)f2bf(a0) | ((unsigned)f2bf(a1) << 16);
    o.y = (unsigned)f2bf(a2) | ((unsigned)f2bf(a3) << 16);
    o.z = (unsigned)f2bf(a4) | ((unsigned)f2bf(a5) << 16);
    o.w = (unsigned)f2bf(a6) | ((unsigned)f2bf(a7) << 16);
    reinterpret_cast<uint4*>(Y)[row * 8 + q] = o;
}

// ===========================================================================
// mlp2: z = Y @ W2 + b2 (fp32 math), store z bf16, BN stats fp32.
// 64 rows/block, 4x4 tile.
// ===========================================================================
__global__ __launch_bounds__(256) void mlp2_kernel(
    const unsigned short* __restrict__ Y, const float* __restrict__ W2,
    const float* __restrict__ b2, unsigned short* __restrict__ zb,
    float* __restrict__ gsum, float* __restrict__ gsq)
{
    constexpr int RPB = 64;
    __shared__ float XsT[64][68];
    __shared__ float Ws[64][64];
    __shared__ float b2s[64], lsum[64], lsq[64];

    const int t = threadIdx.x;
    const int rowbase = blockIdx.x * RPB;

    if (t < 64) { b2s[t] = b2[t]; lsum[t] = 0.f; lsq[t] = 0.f; }

    {
        const float4* wg = reinterpret_cast<const float4*>(W2);
        float4* wl = reinterpret_cast<float4*>(&Ws[0][0]);
        for (int i = t; i < 64 * 16; i += 256) wl[i] = wg[i];
    }
    {
        const uint4* yb = reinterpret_cast<const uint4*>(Y);
        int rr = t & 31, qq = t >> 5;
        for (int i = 0; i < RPB; i += 32) {
            int r = i + rr;
            int gr = rowbase + r;
            uint4 v = make_uint4(0u, 0u, 0u, 0u);
            if (gr < NN) v = yb[gr * 8 + qq];
            int c = qq * 8;
            XsT[c + 0][r] = bflo(v.x); XsT[c + 1][r] = bfhi(v.x);
            XsT[c + 2][r] = bflo(v.y); XsT[c + 3][r] = bfhi(v.y);
            XsT[c + 4][r] = bflo(v.z); XsT[c + 5][r] = bfhi(v.z);
            XsT[c + 6][r] = bflo(v.w); XsT[c + 7][r] = bfhi(v.w);
        }
    }
    __syncthreads();

    const int tc = t & 15;
    const int tr = t >> 4;
    const int c0 = tc * 4;
    const int r0 = tr * 4;

    float acc[4][4];
    #pragma unroll
    for (int i = 0; i < 4; ++i)
        #pragma unroll
        for (int j = 0; j < 4; ++j) acc[i][j] = 0.f;

    for (int k = 0; k < 64; ++k) {
        float4 xa = *reinterpret_cast<const float4*>(&XsT[k][r0]);
        float4 wa = *reinterpret_cast<const float4*>(&Ws[k][c0]);
        float x[4] = { xa.x, xa.y, xa.z, xa.w };
        float w[4] = { wa.x, wa.y, wa.z, wa.w };
        #pragma unroll
        for (int i = 0; i < 4; ++i)
            #pragma unroll
            for (int j = 0; j < 4; ++j) acc[i][j] += x[i] * w[j];
    }

    float s[4], sq[4];
    #pragma unroll
    for (int j = 0; j < 4; ++j) { s[j] = 0.f; sq[j] = 0.f; }

    #pragma unroll
    for (int i = 0; i < 4; ++i) {
        int gr = rowbase + r0 + i;
        if (gr < NN) {
            float zv[4];
            #pragma unroll
            for (int j = 0; j < 4; ++j) {
                zv[j] = acc[i][j] + b2s[c0 + j];
                s[j] += zv[j];
                sq[j] += zv[j] * zv[j];
            }
            unsigned lo = (unsigned)f2bf(zv[0]) | ((unsigned)f2bf(zv[1]) << 16);
            unsigned hi = (unsigned)f2bf(zv[2]) | ((unsigned)f2bf(zv[3]) << 16);
            *reinterpret_cast<uint2*>(zb + (size_t)gr * 64 + c0) = make_uint2(lo, hi);
        }
    }

    // reduce over row-groups: lane bits 4,5 within wave; 4 waves via LDS atomics
    #pragma unroll
    for (int j = 0; j < 4; ++j) {
        s[j]  += __shfl_xor(s[j], 16);
        s[j]  += __shfl_xor(s[j], 32);
        sq[j] += __shfl_xor(sq[j], 16);
        sq[j] += __shfl_xor(sq[j], 32);
    }
    if ((t & 48) == 0) {
        #pragma unroll
        for (int j = 0; j < 4; ++j) {
            atomicAdd(&lsum[c0 + j], s[j]);
            atomicAdd(&lsq[c0 + j], sq[j]);
        }
    }
    __syncthreads();
    if (t < 64) {
        atomicAdd(&gsum[t], lsum[t]);
        atomicAdd(&gsq[t], lsq[t]);
    }
}

// ===========================================================================
// final norm: out(fp32) = relu(zb*scale+shift), zb bf16
// ===========================================================================
__global__ __launch_bounds__(256) void norm_kernel(
    const unsigned short* __restrict__ zb,
    const float* __restrict__ gsum, const float* __restrict__ gsq,
    const float* __restrict__ gamma, const float* __restrict__ beta,
    float* __restrict__ out)
{
    __shared__ float sc[64], sh[64];
    int t = threadIdx.x;
    if (t < 64) {
        const float invn = 1.f / (float)NN;
        float mean = gsum[t] * invn;
        float var  = gsq[t] * invn - mean * mean;
        float s    = gamma[t] * rsqrtf(var + BN_EPS);
        sc[t] = s;
        sh[t] = beta[t] - mean * s;
    }
    __syncthreads();
    int idx = blockIdx.x * 256 + t;
    if (idx >= NN * 8) return;
    int row = idx >> 3;
    int q = idx & 7;
    int c = q * 8;
    uint4 v = reinterpret_cast<const uint4*>(zb)[idx];
    float f0 = bflo(v.x), f1 = bfhi(v.x), f2 = bflo(v.y), f3 = bfhi(v.y);
    float f4 = bflo(v.z), f5 = bfhi(v.z), f6 = bflo(v.w), f7 = bfhi(v.w);
    float4 lo, hi;
    lo.x = fmaxf(f0 * sc[c + 0] + sh[c + 0], 0.f);
    lo.y = fmaxf(f1 * sc[c + 1] + sh[c + 1], 0.f);
    lo.z = fmaxf(f2 * sc[c + 2] + sh[c + 2], 0.f);
    lo.w = fmaxf(f3 * sc[c + 3] + sh[c + 3], 0.f);
    hi.x = fmaxf(f4 * sc[c + 4] + sh[c + 4], 0.f);
    hi.y = fmaxf(f5 * sc[c + 5] + sh[c + 5], 0.f);
    hi.z = fmaxf(f6 * sc[c + 6] + sh[c + 6], 0.f);
    hi.w = fmaxf(f7 * sc[c + 7] + sh[c + 7], 0.f);
    float* o = out + (size_t)row * 64 + c;
    *reinterpret_cast<float4*>(o) = lo;
    *reinterpret_cast<float4*>(o + 4) = hi;
}

// ===========================================================================
extern "C" void kernel_launch(void* const* d_in, const int* in_sizes, int n_in,
                              void* d_out, int out_size, void* d_ws, size_t ws_size,
                              hipStream_t stream)
{
    const float* h    = (const float*)d_in[0];
    const int*   src  = (const int*)d_in[1];
    const int*   dst  = (const int*)d_in[2];
    const float* W1_0 = (const float*)d_in[3];
    const float* b1_0 = (const float*)d_in[4];
    const float* W2_0 = (const float*)d_in[5];
    const float* b2_0 = (const float*)d_in[6];
    const float* g_0  = (const float*)d_in[7];
    const float* be_0 = (const float*)d_in[8];
    const float* W1st = (const float*)d_in[9];
    const float* b1st = (const float*)d_in[10];
    const float* W2st = (const float*)d_in[11];
    const float* b2st = (const float*)d_in[12];
    const float* gst  = (const float*)d_in[13];
    const float* best = (const float*)d_in[14];
    float* out = (float*)d_out;

    char* ws = (char*)d_ws;
    unsigned short* p  = (unsigned short*)ws;                    // NN*64 bf16
    unsigned short* Y  = p + (size_t)NN * 64;                    // NN*64 bf16
    unsigned short* zb = Y + (size_t)NN * 64;                    // NN*64 bf16
    unsigned* tmp = (unsigned*)(zb + (size_t)NN * 64);           // NB*CAP u32
    int* eidx   = (int*)(tmp + (size_t)NB * CAP);                // NE
    float* stats = (float*)(eidx + NE);                          // 512 floats
    int* gcount = (int*)(stats + 512);                           // NB (adjacent)
    int* off    = gcount + NB;                                   // NN+1

    // ---- zero -> [binA || proj0] -> binB ----
    zero_kernel<<<3, 256, 0, stream>>>((int*)stats, 512 + NB);
    fat_kernel<<<BINABLK + PROJ0BLK, 256, 0, stream>>>(
        src, dst, gcount, tmp, h, W1_0, p);
    binB_kernel<<<NB, 256, 0, stream>>>(tmp, gcount, off, eidx);

    const int gemmblk   = (NN + 63) / 64;
    const int gatherblk = (NN * 8 + 255) / 256;
    const int normblk   = (NN * 8 + 255) / 256;

    float* gs0 = stats + 0 * 128;
    gather_kernel<<<gatherblk, 256, 0, stream>>>(p, off, eidx, b1_0, Y);
    mlp2_kernel<<<gemmblk, 256, 0, stream>>>(Y, W2_0, b2_0, zb, gs0, gs0 + 64);

    const float* gammas[4] = { g_0, gst + 0, gst + 64, gst + 128 };
    const float* betas[4]  = { be_0, best + 0, best + 64, best + 128 };

    for (int l = 0; l < 3; ++l) {
        float* gsp = stats + l * 128;
        float* gsc = stats + (l + 1) * 128;
        proj_kernel<<<gemmblk, 256, 0, stream>>>(
            zb, W1st + l * 4096, gsp, gsp + 64, gammas[l], betas[l], p);
        gather_kernel<<<gatherblk, 256, 0, stream>>>(p, off, eidx, b1st + l * 64, Y);
        mlp2_kernel<<<gemmblk, 256, 0, stream>>>(
            Y, W2st + l * 4096, b2st + l * 64, zb, gsc, gsc + 64);
    }

    float* gs3 = stats + 3 * 128;
    norm_kernel<<<normblk, 256, 0, stream>>>(zb, gs3, gs3 + 64, gammas[3], betas[3], out);
}

// Round 17
// 232.175 us; speedup vs baseline: 1.1112x; 1.1112x over previous
//
#include <hip/hip_runtime.h>
#include <hip/hip_bf16.h>

static constexpr int NN = 50000;
static constexpr int NE = 800000;
static constexpr float BN_EPS = 1e-5f;

static constexpr int NB  = 128;    // dst buckets
static constexpr int NPB = 391;    // nodes per bucket
static constexpr int CAP = 8192;   // tmp slots per bucket
static constexpr int CHUNK = 2048;
static constexpr int SRNG = 12500; // src-range width (gather L2 locality)

static constexpr int BINABLK  = (NE + CHUNK - 1) / CHUNK;  // 391
static constexpr int PROJ0BLK = (NN + 63) / 64;            // 782

typedef short bf16x8 __attribute__((ext_vector_type(8)));
typedef float f32x4 __attribute__((ext_vector_type(4)));

__device__ __forceinline__ float bflo(unsigned u) { return __uint_as_float(u << 16); }
__device__ __forceinline__ float bfhi(unsigned u) { return __uint_as_float(u & 0xffff0000u); }
__device__ __forceinline__ unsigned short f2bf(float f) {
    unsigned u = __float_as_uint(f);
    unsigned r = (u + 0x7fffu + ((u >> 16) & 1u)) >> 16;
    return (unsigned short)r;
}

// ===========================================================================
// zero: stats (512 f) + gcount (NB ints), contiguous
// ===========================================================================
__global__ __launch_bounds__(256) void zero_kernel(int* __restrict__ ptr, int n)
{
    int i = blockIdx.x * 256 + threadIdx.x;
    if (i < n) ptr[i] = 0;
}

// ===========================================================================
// fat_kernel: blocks [0,BINABLK) = binA (edge bucketing);
//             blocks [BINABLK, BINABLK+PROJ0BLK) = proj0 (h @ W1_0, MFMA).
// Independent work overlapped in one dispatch. LDS = union (17.4 KB).
// ===========================================================================
struct SmBinA {
    unsigned stage[CHUNK];
    int hist[NB], base[NB], gpos[NB];
};
struct SmProj0 {
    unsigned short Wt[64][136];
};

__device__ __forceinline__ void binA_body(
    SmBinA& sm, const int* __restrict__ src, const int* __restrict__ dst,
    int* __restrict__ gcount, unsigned* __restrict__ tmp, int blk)
{
    const int t = threadIdx.x;
    const int cb = blk * CHUNK;
    const int total = min(CHUNK, NE - cb);

    if (t < NB) sm.hist[t] = 0;
    __syncthreads();

    int mb[8], mslot[8];
    unsigned mv[8];
    #pragma unroll
    for (int k = 0; k < 8; ++k) {
        int e = cb + k * 256 + t;
        mb[k] = -1;
        if (e < NE) {
            int s = src[e];
            int d = dst[e];
            int b = d / NPB;
            mb[k] = b;
            mv[k] = ((unsigned)d << 16) | (unsigned)s;
            mslot[k] = atomicAdd(&sm.hist[b], 1);
        }
    }
    __syncthreads();

    if (t < NB) sm.base[t] = sm.hist[t];
    __syncthreads();
    for (int ofs = 1; ofs < NB; ofs <<= 1) {
        int v = (t >= ofs && t < NB) ? sm.base[t - ofs] : 0;
        __syncthreads();
        if (t < NB) sm.base[t] += v;
        __syncthreads();
    }
    if (t < NB && sm.hist[t] > 0)
        sm.gpos[t] = t * CAP + atomicAdd(&gcount[t], sm.hist[t]);
    __syncthreads();

    #pragma unroll
    for (int k = 0; k < 8; ++k) {
        if (mb[k] >= 0) {
            int b = mb[k];
            sm.stage[(sm.base[b] - sm.hist[b]) + mslot[k]] = mv[k];
        }
    }
    __syncthreads();

    for (int i = t; i < total; i += 256) {
        unsigned v = sm.stage[i];
        int b = (int)(v >> 16) / NPB;
        int pos = sm.gpos[b] + (i - (sm.base[b] - sm.hist[b]));
        tmp[pos] = v;
    }
}

__device__ __forceinline__ void proj0_body(
    SmProj0& sm, const float* __restrict__ hin, const float* __restrict__ W1,
    unsigned short* __restrict__ p, int blk)
{
    const int t = threadIdx.x;
    for (int i = t; i < 128 * 16; i += 256) {
        int k = i >> 4, c0 = (i & 15) * 4;
        float4 w = *reinterpret_cast<const float4*>(W1 + (size_t)k * 64 + c0);
        sm.Wt[c0 + 0][k] = f2bf(w.x); sm.Wt[c0 + 1][k] = f2bf(w.y);
        sm.Wt[c0 + 2][k] = f2bf(w.z); sm.Wt[c0 + 3][k] = f2bf(w.w);
    }
    __syncthreads();

    const int wv = t >> 6;
    const int l = t & 63;
    const int g = l >> 4;
    const int cl = l & 15;
    const int rowbase = blk * 64 + wv * 16;

    int ar = min(rowbase + cl, NN - 1);
    const float* hrow = hin + (size_t)ar * 128;
    bf16x8 a[4];
    #pragma unroll
    for (int kk = 0; kk < 4; ++kk) {
        float4 f0 = *reinterpret_cast<const float4*>(hrow + kk * 32 + 8 * g);
        float4 f1 = *reinterpret_cast<const float4*>(hrow + kk * 32 + 8 * g + 4);
        unsigned short oo[8] = { f2bf(f0.x), f2bf(f0.y), f2bf(f0.z), f2bf(f0.w),
                                 f2bf(f1.x), f2bf(f1.y), f2bf(f1.z), f2bf(f1.w) };
        a[kk] = *reinterpret_cast<bf16x8*>(oo);
    }

    f32x4 acc[4];
    #pragma unroll
    for (int ct = 0; ct < 4; ++ct) acc[ct] = (f32x4){0.f, 0.f, 0.f, 0.f};

    #pragma unroll
    for (int ct = 0; ct < 4; ++ct) {
        #pragma unroll
        for (int kk = 0; kk < 4; ++kk) {
            bf16x8 w = *reinterpret_cast<const bf16x8*>(
                &sm.Wt[ct * 16 + cl][kk * 32 + 8 * g]);
            acc[ct] = __builtin_amdgcn_mfma_f32_16x16x32_bf16(w, a[kk], acc[ct], 0, 0, 0);
        }
    }

    int gr = rowbase + cl;
    if (gr < NN) {
        #pragma unroll
        for (int ct = 0; ct < 4; ++ct) {
            unsigned lo = (unsigned)f2bf(acc[ct][0]) | ((unsigned)f2bf(acc[ct][1]) << 16);
            unsigned hi = (unsigned)f2bf(acc[ct][2]) | ((unsigned)f2bf(acc[ct][3]) << 16);
            *reinterpret_cast<uint2*>(p + (size_t)gr * 64 + ct * 16 + 4 * g) =
                make_uint2(lo, hi);
        }
    }
}

__global__ __launch_bounds__(256) void fat_kernel(
    const int* __restrict__ src, const int* __restrict__ dst,
    int* __restrict__ gcount, unsigned* __restrict__ tmp,
    const float* __restrict__ hin, const float* __restrict__ W1,
    unsigned short* __restrict__ p)
{
    __shared__ union { SmBinA a; SmProj0 w; } sm;
    if (blockIdx.x < BINABLK)
        binA_body(sm.a, src, dst, gcount, tmp, blockIdx.x);
    else
        proj0_body(sm.w, hin, W1, p, blockIdx.x - BINABLK);
}

// ===========================================================================
// binB: per bucket: per-(node,src-range) hist + scan -> off + src-ordered eidx
// ===========================================================================
__global__ __launch_bounds__(256) void binB_kernel(
    const unsigned* __restrict__ tmp, const int* __restrict__ gcount,
    int* __restrict__ off, int* __restrict__ eidx)
{
    __shared__ int gb[NB];
    __shared__ int hist4[NPB * 4];
    __shared__ int hs[512];
    __shared__ int cur4[NPB * 4];
    __shared__ int base_s;

    const int t = threadIdx.x;
    const int b = blockIdx.x;
    const int n0 = b * NPB;
    const int n1 = min(n0 + NPB, NN);
    const int nnodes = n1 - n0;
    const int cnt = gcount[b];

    if (t < NB) gb[t] = gcount[t];
    for (int i = t; i < NPB * 4; i += 256) hist4[i] = 0;
    __syncthreads();
    for (int ofs = 1; ofs < NB; ofs <<= 1) {
        int v = (t >= ofs && t < NB) ? gb[t - ofs] : 0;
        __syncthreads();
        if (t < NB) gb[t] += v;
        __syncthreads();
    }
    if (t == 0) base_s = (b == 0) ? 0 : gb[b - 1];
    __syncthreads();
    const int base = base_s;

    const unsigned* tb = tmp + (size_t)b * CAP;
    for (int i = t; i < cnt; i += 256) {
        unsigned v = tb[i];
        int d = (int)(v >> 16);
        int s = (int)(v & 0xffffu);
        atomicAdd(&hist4[(d - n0) * 4 + s / SRNG], 1);
    }
    __syncthreads();
    {
        int n = t;
        hs[t] = (n < NPB) ? (hist4[n * 4] + hist4[n * 4 + 1] +
                             hist4[n * 4 + 2] + hist4[n * 4 + 3]) : 0;
        n = t + 256;
        hs[t + 256] = (n < NPB) ? (hist4[n * 4] + hist4[n * 4 + 1] +
                                   hist4[n * 4 + 2] + hist4[n * 4 + 3]) : 0;
    }
    __syncthreads();
    for (int ofs = 1; ofs < 512; ofs <<= 1) {
        int a0 = (t >= ofs) ? hs[t - ofs] : 0;
        int a1 = hs[t + 256 - ofs];
        __syncthreads();
        hs[t] += a0;
        hs[t + 256] += a1;
        __syncthreads();
    }
    for (int n = t; n < nnodes; n += 256) {
        int h0 = hist4[n * 4], h1 = hist4[n * 4 + 1], h2 = hist4[n * 4 + 2];
        int tot = h0 + h1 + h2 + hist4[n * 4 + 3];
        int c = base + hs[n] - tot;
        off[n0 + n] = c;
        cur4[n * 4 + 0] = c; c += h0;
        cur4[n * 4 + 1] = c; c += h1;
        cur4[n * 4 + 2] = c; c += h2;
        cur4[n * 4 + 3] = c;
    }
    if (b == NB - 1 && t == 0) off[NN] = base + cnt;
    __syncthreads();
    for (int i = t; i < cnt; i += 256) {
        unsigned v = tb[i];
        int d = (int)(v >> 16);
        int s = (int)(v & 0xffffu);
        int pos = atomicAdd(&cur4[(d - n0) * 4 + s / SRNG], 1);
        eidx[pos] = s;
    }
}

// ===========================================================================
// proj (layers 1-3): p(bf16) = relu(zb*scale+shift) @ W1, fp32 4x8 tile.
// 128 rows/block.
// ===========================================================================
__global__ __launch_bounds__(256) void proj_kernel(
    const unsigned short* __restrict__ zbin, const float* __restrict__ W1,
    const float* __restrict__ gsum, const float* __restrict__ gsq,
    const float* __restrict__ gamma, const float* __restrict__ beta,
    unsigned short* __restrict__ p)
{
    constexpr int RPB = 128;
    __shared__ float XsT[64][132];
    __shared__ float Ws[64][64];
    __shared__ float scs[64], shs[64];

    const int t = threadIdx.x;
    const int rowbase = blockIdx.x * RPB;

    if (t < 64) {
        const float invn = 1.f / (float)NN;
        float mean = gsum[t] * invn;
        float var  = gsq[t] * invn - mean * mean;
        float sc   = gamma[t] * rsqrtf(var + BN_EPS);
        scs[t] = sc;
        shs[t] = beta[t] - mean * sc;
    }
    __syncthreads();

    const int tc = t & 7;
    const int tr = t >> 3;
    const int c0 = tc * 8;
    const int r0 = tr * 4;

    float acc[4][8];
    #pragma unroll
    for (int i = 0; i < 4; ++i)
        #pragma unroll
        for (int j = 0; j < 8; ++j) acc[i][j] = 0.f;

    {
        const float4* wg = reinterpret_cast<const float4*>(W1);
        float4* wl = reinterpret_cast<float4*>(&Ws[0][0]);
        for (int i = t; i < 64 * 16; i += 256) wl[i] = wg[i];
    }
    {
        const uint4* hb = reinterpret_cast<const uint4*>(zbin);
        int rr = t & 31, q = t >> 5;
        for (int i = 0; i < RPB; i += 32) {
            int r = i + rr;
            int gr = rowbase + r;
            uint4 v = make_uint4(0u, 0u, 0u, 0u);
            if (gr < NN) v = hb[gr * 8 + q];
            int c = q * 8;
            float f0 = bflo(v.x), f1 = bfhi(v.x), f2 = bflo(v.y), f3 = bfhi(v.y);
            float f4 = bflo(v.z), f5 = bfhi(v.z), f6 = bflo(v.w), f7 = bfhi(v.w);
            XsT[c + 0][r] = fmaxf(f0 * scs[c + 0] + shs[c + 0], 0.f);
            XsT[c + 1][r] = fmaxf(f1 * scs[c + 1] + shs[c + 1], 0.f);
            XsT[c + 2][r] = fmaxf(f2 * scs[c + 2] + shs[c + 2], 0.f);
            XsT[c + 3][r] = fmaxf(f3 * scs[c + 3] + shs[c + 3], 0.f);
            XsT[c + 4][r] = fmaxf(f4 * scs[c + 4] + shs[c + 4], 0.f);
            XsT[c + 5][r] = fmaxf(f5 * scs[c + 5] + shs[c + 5], 0.f);
            XsT[c + 6][r] = fmaxf(f6 * scs[c + 6] + shs[c + 6], 0.f);
            XsT[c + 7][r] = fmaxf(f7 * scs[c + 7] + shs[c + 7], 0.f);
        }
    }
    __syncthreads();

    for (int k = 0; k < 64; ++k) {
        float4 xa = *reinterpret_cast<const float4*>(&XsT[k][r0]);
        float4 wa = *reinterpret_cast<const float4*>(&Ws[k][c0]);
        float4 wb = *reinterpret_cast<const float4*>(&Ws[k][c0 + 4]);
        float x[4] = { xa.x, xa.y, xa.z, xa.w };
        float w[8] = { wa.x, wa.y, wa.z, wa.w, wb.x, wb.y, wb.z, wb.w };
        #pragma unroll
        for (int i = 0; i < 4; ++i)
            #pragma unroll
            for (int j = 0; j < 8; ++j) acc[i][j] += x[i] * w[j];
    }

    #pragma unroll
    for (int i = 0; i < 4; ++i) {
        int gr = rowbase + r0 + i;
        if (gr < NN) {
            uint4 u;
            u.x = (unsigned)f2bf(acc[i][0]) | ((unsigned)f2bf(acc[i][1]) << 16);
            u.y = (unsigned)f2bf(acc[i][2]) | ((unsigned)f2bf(acc[i][3]) << 16);
            u.z = (unsigned)f2bf(acc[i][4]) | ((unsigned)f2bf(acc[i][5]) << 16);
            u.w = (unsigned)f2bf(acc[i][6]) | ((unsigned)f2bf(acc[i][7]) << 16);
            *reinterpret_cast<uint4*>(p + (size_t)gr * 64 + c0) = u;
        }
    }
}

// ===========================================================================
// gather: Y[i] = relu(p[i] + sum_{j in N(i)} p[j] + b1)   (bf16 in/out)
// ===========================================================================
__global__ __launch_bounds__(256) void gather_kernel(
    const unsigned short* __restrict__ p, const int* __restrict__ off,
    const int* __restrict__ eidx, const float* __restrict__ b1,
    unsigned short* __restrict__ Y)
{
    int gid = blockIdx.x * 256 + threadIdx.x;
    if (gid >= NN * 8) return;
    int row = gid >> 3;
    int q = gid & 7;

    const uint4* pb = reinterpret_cast<const uint4*>(p);
    uint4 u = pb[row * 8 + q];
    float a0 = bflo(u.x), a1 = bfhi(u.x), a2 = bflo(u.y), a3 = bfhi(u.y);
    float a4 = bflo(u.z), a5 = bfhi(u.z), a6 = bflo(u.w), a7 = bfhi(u.w);

    int e = off[row];
    const int end = off[row + 1];
    for (; e + 4 <= end; e += 4) {
        int s0 = eidx[e + 0], s1 = eidx[e + 1];
        int s2 = eidx[e + 2], s3 = eidx[e + 3];
        uint4 v0 = pb[s0 * 8 + q];
        uint4 v1 = pb[s1 * 8 + q];
        uint4 v2 = pb[s2 * 8 + q];
        uint4 v3 = pb[s3 * 8 + q];
        a0 += (bflo(v0.x) + bflo(v1.x)) + (bflo(v2.x) + bflo(v3.x));
        a1 += (bfhi(v0.x) + bfhi(v1.x)) + (bfhi(v2.x) + bfhi(v3.x));
        a2 += (bflo(v0.y) + bflo(v1.y)) + (bflo(v2.y) + bflo(v3.y));
        a3 += (bfhi(v0.y) + bfhi(v1.y)) + (bfhi(v2.y) + bfhi(v3.y));
        a4 += (bflo(v0.z) + bflo(v1.z)) + (bflo(v2.z) + bflo(v3.z));
        a5 += (bfhi(v0.z) + bfhi(v1.z)) + (bfhi(v2.z) + bfhi(v3.z));
        a6 += (bflo(v0.w) + bflo(v1.w)) + (bflo(v2.w) + bflo(v3.w));
        a7 += (bfhi(v0.w) + bfhi(v1.w)) + (bfhi(v2.w) + bfhi(v3.w));
    }
    for (; e < end; ++e) {
        uint4 v = pb[eidx[e] * 8 + q];
        a0 += bflo(v.x); a1 += bfhi(v.x); a2 += bflo(v.y); a3 += bfhi(v.y);
        a4 += bflo(v.z); a5 += bfhi(v.z); a6 += bflo(v.w); a7 += bfhi(v.w);
    }

    float4 blo = reinterpret_cast<const float4*>(b1)[q * 2];
    float4 bhi = reinterpret_cast<const float4*>(b1)[q * 2 + 1];
    a0 = fmaxf(a0 + blo.x, 0.f); a1 = fmaxf(a1 + blo.y, 0.f);
    a2 = fmaxf(a2 + blo.z, 0.f); a3 = fmaxf(a3 + blo.w, 0.f);
    a4 = fmaxf(a4 + bhi.x, 0.f); a5 = fmaxf(a5 + bhi.y, 0.f);
    a6 = fmaxf(a6 + bhi.z, 0.f); a7 = fmaxf(a7 + bhi.w, 0.f);

    uint4 o;
    o.x = (unsigned)f2bf(a0) | ((unsigned)f2bf(a1) << 16);
    o.y = (unsigned)f2bf(a2) | ((unsigned)f2bf(a3) << 16);
    o.z = (unsigned)f2bf(a4) | ((unsigned)f2bf(a5) << 16);
    o.w = (unsigned)f2bf(a6) | ((unsigned)f2bf(a7) << 16);
    reinterpret_cast<uint4*>(Y)[row * 8 + q] = o;
}

// ===========================================================================
// mlp2: z = Y @ W2 + b2 (Y bf16 -> fp32 math), store z as bf16, BN stats fp32.
// ===========================================================================
__global__ __launch_bounds__(256) void mlp2_kernel(
    const unsigned short* __restrict__ Y, const float* __restrict__ W2,
    const float* __restrict__ b2, unsigned short* __restrict__ zb,
    float* __restrict__ gsum, float* __restrict__ gsq)
{
    constexpr int RPB = 128;
    __shared__ float XsT[64][132];
    __shared__ float Ws[64][64];
    __shared__ float b2s[64], lsum[64], lsq[64];

    const int t = threadIdx.x;
    const int rowbase = blockIdx.x * RPB;

    if (t < 64) { b2s[t] = b2[t]; lsum[t] = 0.f; lsq[t] = 0.f; }

    {
        const float4* wg = reinterpret_cast<const float4*>(W2);
        float4* wl = reinterpret_cast<float4*>(&Ws[0][0]);
        for (int i = t; i < 64 * 16; i += 256) wl[i] = wg[i];
    }
    {
        const uint4* yb = reinterpret_cast<const uint4*>(Y);
        int rr = t & 31, qq = t >> 5;
        for (int i = 0; i < RPB; i += 32) {
            int r = i + rr;
            int gr = rowbase + r;
            uint4 v = make_uint4(0u, 0u, 0u, 0u);
            if (gr < NN) v = yb[gr * 8 + qq];
            int c = qq * 8;
            XsT[c + 0][r] = bflo(v.x); XsT[c + 1][r] = bfhi(v.x);
            XsT[c + 2][r] = bflo(v.y); XsT[c + 3][r] = bfhi(v.y);
            XsT[c + 4][r] = bflo(v.z); XsT[c + 5][r] = bfhi(v.z);
            XsT[c + 6][r] = bflo(v.w); XsT[c + 7][r] = bfhi(v.w);
        }
    }
    __syncthreads();

    const int tc = t & 7;
    const int tr = t >> 3;
    const int c0 = tc * 8;
    const int r0 = tr * 4;

    float acc[4][8];
    #pragma unroll
    for (int i = 0; i < 4; ++i)
        #pragma unroll
        for (int j = 0; j < 8; ++j) acc[i][j] = 0.f;

    for (int k = 0; k < 64; ++k) {
        float4 xa = *reinterpret_cast<const float4*>(&XsT[k][r0]);
        float4 wa = *reinterpret_cast<const float4*>(&Ws[k][c0]);
        float4 wb = *reinterpret_cast<const float4*>(&Ws[k][c0 + 4]);
        float x[4] = { xa.x, xa.y, xa.z, xa.w };
        float w[8] = { wa.x, wa.y, wa.z, wa.w, wb.x, wb.y, wb.z, wb.w };
        #pragma unroll
        for (int i = 0; i < 4; ++i)
            #pragma unroll
            for (int j = 0; j < 8; ++j) acc[i][j] += x[i] * w[j];
    }

    float s[8], sq[8];
    #pragma unroll
    for (int j = 0; j < 8; ++j) { s[j] = 0.f; sq[j] = 0.f; }

    #pragma unroll
    for (int i = 0; i < 4; ++i) {
        int gr = rowbase + r0 + i;
        if (gr < NN) {
            float zv[8];
            #pragma unroll
            for (int j = 0; j < 8; ++j) {
                zv[j] = acc[i][j] + b2s[c0 + j];
                s[j] += zv[j];
                sq[j] += zv[j] * zv[j];
            }
            uint4 o;
            o.x = (unsigned)f2bf(zv[0]) | ((unsigned)f2bf(zv[1]) << 16);
            o.y = (unsigned)f2bf(zv[2]) | ((unsigned)f2bf(zv[3]) << 16);
            o.z = (unsigned)f2bf(zv[4]) | ((unsigned)f2bf(zv[5]) << 16);
            o.w = (unsigned)f2bf(zv[6]) | ((unsigned)f2bf(zv[7]) << 16);
            *reinterpret_cast<uint4*>(zb + (size_t)gr * 64 + c0) = o;
        }
    }

    #pragma unroll
    for (int j = 0; j < 8; ++j) {
        s[j]  += __shfl_xor(s[j], 8);
        s[j]  += __shfl_xor(s[j], 16);
        s[j]  += __shfl_xor(s[j], 32);
        sq[j] += __shfl_xor(sq[j], 8);
        sq[j] += __shfl_xor(sq[j], 16);
        sq[j] += __shfl_xor(sq[j], 32);
    }
    if ((t & 56) == 0) {
        #pragma unroll
        for (int j = 0; j < 8; ++j) {
            atomicAdd(&lsum[c0 + j], s[j]);
            atomicAdd(&lsq[c0 + j], sq[j]);
        }
    }
    __syncthreads();
    if (t < 64) {
        atomicAdd(&gsum[t], lsum[t]);
        atomicAdd(&gsq[t], lsq[t]);
    }
}

// ===========================================================================
// final norm: out(fp32) = relu(zb*scale+shift), zb bf16
// ===========================================================================
__global__ __launch_bounds__(256) void norm_kernel(
    const unsigned short* __restrict__ zb,
    const float* __restrict__ gsum, const float* __restrict__ gsq,
    const float* __restrict__ gamma, const float* __restrict__ beta,
    float* __restrict__ out)
{
    __shared__ float sc[64], sh[64];
    int t = threadIdx.x;
    if (t < 64) {
        const float invn = 1.f / (float)NN;
        float mean = gsum[t] * invn;
        float var  = gsq[t] * invn - mean * mean;
        float s    = gamma[t] * rsqrtf(var + BN_EPS);
        sc[t] = s;
        sh[t] = beta[t] - mean * s;
    }
    __syncthreads();
    int idx = blockIdx.x * 256 + t;
    if (idx >= NN * 8) return;
    int row = idx >> 3;
    int q = idx & 7;
    int c = q * 8;
    uint4 v = reinterpret_cast<const uint4*>(zb)[idx];
    float f0 = bflo(v.x), f1 = bfhi(v.x), f2 = bflo(v.y), f3 = bfhi(v.y);
    float f4 = bflo(v.z), f5 = bfhi(v.z), f6 = bflo(v.w), f7 = bfhi(v.w);
    float4 lo, hi;
    lo.x = fmaxf(f0 * sc[c + 0] + sh[c + 0], 0.f);
    lo.y = fmaxf(f1 * sc[c + 1] + sh[c + 1], 0.f);
    lo.z = fmaxf(f2 * sc[c + 2] + sh[c + 2], 0.f);
    lo.w = fmaxf(f3 * sc[c + 3] + sh[c + 3], 0.f);
    hi.x = fmaxf(f4 * sc[c + 4] + sh[c + 4], 0.f);
    hi.y = fmaxf(f5 * sc[c + 5] + sh[c + 5], 0.f);
    hi.z = fmaxf(f6 * sc[c + 6] + sh[c + 6], 0.f);
    hi.w = fmaxf(f7 * sc[c + 7] + sh[c + 7], 0.f);
    float* o = out + (size_t)row * 64 + c;
    *reinterpret_cast<float4*>(o) = lo;
    *reinterpret_cast<float4*>(o + 4) = hi;
}

// ===========================================================================
extern "C" void kernel_launch(void* const* d_in, const int* in_sizes, int n_in,
                              void* d_out, int out_size, void* d_ws, size_t ws_size,
                              hipStream_t stream)
{
    const float* h    = (const float*)d_in[0];
    const int*   src  = (const int*)d_in[1];
    const int*   dst  = (const int*)d_in[2];
    const float* W1_0 = (const float*)d_in[3];
    const float* b1_0 = (const float*)d_in[4];
    const float* W2_0 = (const float*)d_in[5];
    const float* b2_0 = (const float*)d_in[6];
    const float* g_0  = (const float*)d_in[7];
    const float* be_0 = (const float*)d_in[8];
    const float* W1st = (const float*)d_in[9];
    const float* b1st = (const float*)d_in[10];
    const float* W2st = (const float*)d_in[11];
    const float* b2st = (const float*)d_in[12];
    const float* gst  = (const float*)d_in[13];
    const float* best = (const float*)d_in[14];
    float* out = (float*)d_out;

    char* ws = (char*)d_ws;
    unsigned short* p  = (unsigned short*)ws;                    // NN*64 bf16
    unsigned short* Y  = p + (size_t)NN * 64;                    // NN*64 bf16
    unsigned short* zb = Y + (size_t)NN * 64;                    // NN*64 bf16
    unsigned* tmp = (unsigned*)(zb + (size_t)NN * 64);           // NB*CAP u32
    int* eidx   = (int*)(tmp + (size_t)NB * CAP);                // NE
    float* stats = (float*)(eidx + NE);                          // 512 floats
    int* gcount = (int*)(stats + 512);                           // NB (adjacent)
    int* off    = gcount + NB;                                   // NN+1

    // ---- zero -> [binA || proj0] -> binB ----
    zero_kernel<<<3, 256, 0, stream>>>((int*)stats, 512 + NB);
    fat_kernel<<<BINABLK + PROJ0BLK, 256, 0, stream>>>(
        src, dst, gcount, tmp, h, W1_0, p);
    binB_kernel<<<NB, 256, 0, stream>>>(tmp, gcount, off, eidx);

    const int gemmblk   = (NN + 127) / 128;
    const int gatherblk = (NN * 8 + 255) / 256;
    const int normblk   = (NN * 8 + 255) / 256;

    float* gs0 = stats + 0 * 128;
    gather_kernel<<<gatherblk, 256, 0, stream>>>(p, off, eidx, b1_0, Y);
    mlp2_kernel<<<gemmblk, 256, 0, stream>>>(Y, W2_0, b2_0, zb, gs0, gs0 + 64);

    const float* gammas[4] = { g_0, gst + 0, gst + 64, gst + 128 };
    const float* betas[4]  = { be_0, best + 0, best + 64, best + 128 };

    for (int l = 0; l < 3; ++l) {
        float* gsp = stats + l * 128;
        float* gsc = stats + (l + 1) * 128;
        proj_kernel<<<gemmblk, 256, 0, stream>>>(
            zb, W1st + l * 4096, gsp, gsp + 64, gammas[l], betas[l], p);
        gather_kernel<<<gatherblk, 256, 0, stream>>>(p, off, eidx, b1st + l * 64, Y);
        mlp2_kernel<<<gemmblk, 256, 0, stream>>>(
            Y, W2st + l * 4096, b2st + l * 64, zb, gsc, gsc + 64);
    }

    float* gs3 = stats + 3 * 128;
    norm_kernel<<<normblk, 256, 0, stream>>>(zb, gs3, gs3 + 64, gammas[3], betas[3], out);
}